// Round 12
// baseline (130.104 us; speedup 1.0000x reference)
//
#include <hip/hip_runtime.h>
#include <math.h>

#define FS 4096
#define FT 4096
#define TS 1024          // candidates per LDS tile (float4 -> 16 KB)
#define BIGF 3.0e38f
#define KEYINF 0xFFFFFFFFu

__device__ __forceinline__ unsigned umin32(unsigned a, unsigned b) { return a < b ? a : b; }
__device__ __forceinline__ unsigned umax32(unsigned a, unsigned b) { return a < b ? b : a; }

// v_med3_u32: median of 3 — one VOP3 instruction on gfx950
__device__ __forceinline__ unsigned med3u(unsigned a, unsigned b, unsigned c) {
    unsigned d;
    asm("v_med3_u32 %0, %1, %2, %3" : "=v"(d) : "v"(a), "v"(b), "v"(c));
    return d;
}

// ---------- block reduction helper (all threads must call) ----------
__device__ __forceinline__ float block_reduce_sum(float v) {
    __shared__ float s[8];
    for (int o = 32; o > 0; o >>= 1) v += __shfl_down(v, o, 64);
    int lane = threadIdx.x & 63, wid = threadIdx.x >> 6;
    if (lane == 0) s[wid] = v;
    __syncthreads();
    int nw = blockDim.x >> 6;
    v = (threadIdx.x < (unsigned)nw) ? s[threadIdx.x] : 0.f;
    if (wid == 0)
        for (int o = 4; o > 0; o >>= 1) v += __shfl_down(v, o, 64);
    return v;  // valid in thread 0
}

// compare-exchange on packed keys
#define CE(x, y) { unsigned _n = umin32(x, y); y = umax32(x, y); x = _n; }

// bitonic merge across 32-lane seg groups of sorted-6 lists (INF-pad to 8);
// all lanes end with the merged top-6.
__device__ __forceinline__ void merge32(unsigned s[6]) {
    #pragma unroll
    for (int m = 1; m <= 16; m <<= 1) {
        unsigned b0 = __shfl_xor(s[0], m, 64), b1 = __shfl_xor(s[1], m, 64);
        unsigned b2 = __shfl_xor(s[2], m, 64), b3 = __shfl_xor(s[3], m, 64);
        unsigned b4 = __shfl_xor(s[4], m, 64), b5 = __shfl_xor(s[5], m, 64);
        unsigned l0 = s[0], l1 = s[1];
        unsigned l2 = umin32(s[2], b5), l3 = umin32(s[3], b4);
        unsigned l4 = umin32(s[4], b3), l5 = umin32(s[5], b2);
        unsigned l6 = b1, l7 = b0;
        CE(l0, l4) CE(l1, l5) CE(l2, l6) CE(l3, l7)
        CE(l0, l2) CE(l1, l3) CE(l4, l6) CE(l5, l7)
        CE(l0, l1) CE(l2, l3) CE(l4, l5) CE(l6, l7)
        s[0] = l0; s[1] = l1; s[2] = l2; s[3] = l3; s[4] = l4; s[5] = l5;
    }
}

// ---------- precompute barycenters; zero the output accumulator ----------
// sbc2/tbc2: candidate form (-2x, -2y, -2z, |c|^2)  => dist = p2 + dot3(p, c.xyz) + c.w
// sbcr: raw source barycenter with .w = |bc|^2 (forward query points)
__global__ __launch_bounds__(256) void k_prep(
        const float* __restrict__ sv, const int* __restrict__ sf,
        const float* __restrict__ tv, const int* __restrict__ tf,
        float4* __restrict__ sbc2, float4* __restrict__ tbc2,
        float4* __restrict__ sbcr, float* __restrict__ out) {
    int i = blockIdx.x * blockDim.x + threadIdx.x;
    if (i == 0) out[0] = 0.f;
    if (i >= FS) return;
    const float third = 1.f / 3.f;
    int a = sf[3*i], b = sf[3*i+1], c = sf[3*i+2];
    float x = (sv[3*a  ] + sv[3*b  ] + sv[3*c  ]) * third;
    float y = (sv[3*a+1] + sv[3*b+1] + sv[3*c+1]) * third;
    float z = (sv[3*a+2] + sv[3*b+2] + sv[3*c+2]) * third;
    float n2 = x*x + y*y + z*z;
    sbc2[i] = make_float4(-2.f*x, -2.f*y, -2.f*z, n2);
    sbcr[i] = make_float4(x, y, z, n2);
    int ta = tf[i], tb = tf[FT + i], tc = tf[2*FT + i];
    float tx = (tv[3*ta  ] + tv[3*tb  ] + tv[3*tc  ]) * third;
    float ty = (tv[3*ta+1] + tv[3*tb+1] + tv[3*tc+1]) * third;
    float tz = (tv[3*ta+2] + tv[3*tb+2] + tv[3*tc+2]) * third;
    tbc2[i] = make_float4(-2.f*tx, -2.f*ty, -2.f*tz, tx*tx + ty*ty + tz*tz);
}

// ---------- fused main kernel: 1152 blocks x 256 threads, LDS-staged ----------
// Software-pipelined: global loads for phase p+1 issued before scanning
// phase p (prefetch registers), ds_write at phase head.
// 256 threads = 8 slots x 32 segments. Each slot owns 4 points (or 4 faces).
// blocks [0,1024)    : reverse loss — 32 points/block (4 src + 4 tgt phases)
// blocks [1024,1152) : forward loss — 32 faces/block (4 tgt phases)
__global__ __launch_bounds__(256, 4) void k_main(
        const float* __restrict__ sv, const int* __restrict__ sf,
        const float* __restrict__ fp,
        const float* __restrict__ r1u, const float* __restrict__ r2u,
        const float4* __restrict__ sbc2, const float4* __restrict__ tbc2,
        const float4* __restrict__ sbcr, float* __restrict__ out) {
    __shared__ float4 tile[TS];
    int tid  = threadIdx.x;
    int seg  = tid & 31;
    int slot = tid >> 5;
    float contrib = 0.f;

    if (blockIdx.x < 1024) {
        // ================= reverse =================
        int pt0  = blockIdx.x * 32 + slot * 4;   // this thread's 4 points
        int face = pt0 >> 3;                      // all 4 share one face

        int a = sf[3*face], b = sf[3*face+1], c = sf[3*face+2];
        float ax = sv[3*a], ay = sv[3*a+1], az = sv[3*a+2];
        float bx = sv[3*b], by = sv[3*b+1], bz = sv[3*b+2];
        float cx = sv[3*c], cy = sv[3*c+1], cz = sv[3*c+2];
        float4 r14 = ((const float4*)r1u)[pt0 >> 2];
        float4 r24 = ((const float4*)r2u)[pt0 >> 2];
        float px[4], py[4], pz[4], p2[4];
        {
            float r1a[4] = {r14.x, r14.y, r14.z, r14.w};
            float r2a[4] = {r24.x, r24.y, r24.z, r24.w};
            #pragma unroll
            for (int i = 0; i < 4; ++i) {
                float r1 = sqrtf(r1a[i]);
                float w1 = 1.f - r1, w2 = r1 * (1.f - r2a[i]), w3 = r1 * r2a[i];
                px[i] = w1*ax + w2*bx + w3*cx;
                py[i] = w1*ay + w2*by + w3*cy;
                pz[i] = w1*az + w2*bz + w3*cz;
                p2[i] = px[i]*px[i] + py[i]*py[i] + pz[i]*pz[i];
            }
        }

        // per-lane top-3 per point (min + 2 med3 per eval); exact merged top-6
        unsigned s0[4], s1[4], s2[4];
        #pragma unroll
        for (int i = 0; i < 4; ++i) { s0[i]=KEYINF; s1[i]=KEYINF; s2[i]=KEYINF; }
        float vm[4] = {BIGF, BIGF, BIGF, BIGF};

        // prefetch phase 0 into registers
        float4 pre[4];
        #pragma unroll
        for (int j = 0; j < 4; ++j) pre[j] = sbc2[tid + j*256];

        // 8 phases: 0..3 = src tiles (sort), 4..7 = tgt tiles (min)
        for (int p = 0; p < 8; ++p) {
            #pragma unroll
            for (int j = 0; j < 4; ++j) tile[tid + j*256] = pre[j];
            __syncthreads();
            if (p < 7) {
                const float4* nxt = (p < 3) ? (sbc2 + (p + 1) * TS)
                                            : (tbc2 + (p - 3) * TS);
                #pragma unroll
                for (int j = 0; j < 4; ++j) pre[j] = nxt[tid + j*256];
            }
            if (p < 4) {
                unsigned jj = (unsigned)(p * TS + seg);
                #pragma unroll 2
                for (int jp = 0; jp < TS/32; ++jp) {
                    float4 c4 = tile[(jp << 5) + seg];
                    #pragma unroll
                    for (int i = 0; i < 4; ++i) {
                        // d = |p-c|^2 (unclamped; tiny-negative rounding sorts last)
                        float d = fmaf(px[i], c4.x, fmaf(py[i], c4.y,
                                  fmaf(pz[i], c4.z, c4.w + p2[i])));
                        unsigned k = (__float_as_uint(d) & 0xFFFFF000u) | jj;
                        unsigned n0 = umin32(s0[i], k);
                        unsigned n1 = med3u(s0[i], s1[i], k);
                        unsigned n2 = med3u(s1[i], s2[i], k);
                        s0[i]=n0; s1[i]=n1; s2[i]=n2;
                    }
                    jj += 32;
                }
            } else {
                #pragma unroll 2
                for (int jp = 0; jp < TS/32; ++jp) {
                    float4 c4 = tile[(jp << 5) + seg];
                    #pragma unroll
                    for (int i = 0; i < 4; ++i) {
                        float v = fmaf(px[i], c4.x, fmaf(py[i], c4.y, fmaf(pz[i], c4.z, c4.w)));
                        vm[i] = fminf(vm[i], v);
                    }
                }
            }
            __syncthreads();
        }

        // ---- merges across the 32-lane seg group ----
        #pragma unroll
        for (int i = 0; i < 4; ++i) {
            float v = vm[i];
            v = fminf(v, __shfl_xor(v, 1, 64));
            v = fminf(v, __shfl_xor(v, 2, 64));
            v = fminf(v, __shfl_xor(v, 4, 64));
            v = fminf(v, __shfl_xor(v, 8, 64));
            v = fminf(v, __shfl_xor(v, 16, 64));
            vm[i] = v;
        }

        float pf = fp[face];
        float csum = 0.f;
        #pragma unroll
        for (int i = 0; i < 4; ++i) {
            unsigned srt[6] = {s0[i], s1[i], s2[i], KEYINF, KEYINF, KEYINF};
            merge32(srt);
            if (seg == 0) {
                int   q0 = srt[0] & 0xFFF, q1 = srt[1] & 0xFFF, q2 = srt[2] & 0xFFF;
                int   q3 = srt[3] & 0xFFF, q4 = srt[4] & 0xFFF, q5 = srt[5] & 0xFFF;
                float d0 = __uint_as_float(srt[0] & 0xFFFFF000u);
                float d1 = __uint_as_float(srt[1] & 0xFFFFF000u);
                float d2 = __uint_as_float(srt[2] & 0xFFFFF000u);
                float d3 = __uint_as_float(srt[3] & 0xFFFFF000u);
                float d4 = __uint_as_float(srt[4] & 0xFFFFF000u);
                float d5 = __uint_as_float(srt[5] & 0xFFFFF000u);

                int skip = 5;
                if      (q0 == face) skip = 0;
                else if (q1 == face) skip = 1;
                else if (q2 == face) skip = 2;
                else if (q3 == face) skip = 3;
                else if (q4 == face) skip = 4;

                float s = 0.f;
                if (skip != 0) s += fp[q0] * d0;
                if (skip != 1) s += fp[q1] * d1;
                if (skip != 2) s += fp[q2] * d2;
                if (skip != 3) s += fp[q3] * d3;
                if (skip != 4) s += fp[q4] * d4;
                if (skip != 5) s += fp[q5] * d5;

                float mtd = fmaxf(vm[i] + p2[i], 0.f);
                csum += pf * mtd + (1.f - pf) * (s * 0.2f);
            }
        }
        if (seg == 0) contrib = csum;
    } else {
        // ================= forward =================
        int f0 = (blockIdx.x - 1024) * 32 + slot * 4;   // this thread's 4 faces
        float4 q0 = sbcr[f0], q1 = sbcr[f0+1], q2 = sbcr[f0+2], q3 = sbcr[f0+3];
        float v0 = BIGF, v1 = BIGF, v2 = BIGF, v3 = BIGF;

        float4 pre[4];
        #pragma unroll
        for (int j = 0; j < 4; ++j) pre[j] = tbc2[tid + j*256];

        for (int p = 0; p < 4; ++p) {
            #pragma unroll
            for (int j = 0; j < 4; ++j) tile[tid + j*256] = pre[j];
            __syncthreads();
            if (p < 3) {
                const float4* nxt = tbc2 + (p + 1) * TS;
                #pragma unroll
                for (int j = 0; j < 4; ++j) pre[j] = nxt[tid + j*256];
            }
            #pragma unroll 2
            for (int jp = 0; jp < TS/32; ++jp) {
                float4 c4 = tile[(jp << 5) + seg];
                v0 = fminf(v0, fmaf(q0.x, c4.x, fmaf(q0.y, c4.y, fmaf(q0.z, c4.z, c4.w))));
                v1 = fminf(v1, fmaf(q1.x, c4.x, fmaf(q1.y, c4.y, fmaf(q1.z, c4.z, c4.w))));
                v2 = fminf(v2, fmaf(q2.x, c4.x, fmaf(q2.y, c4.y, fmaf(q2.z, c4.z, c4.w))));
                v3 = fminf(v3, fmaf(q3.x, c4.x, fmaf(q3.y, c4.y, fmaf(q3.z, c4.z, c4.w))));
            }
            __syncthreads();
        }
        #pragma unroll
        for (int m = 1; m <= 16; m <<= 1) {
            v0 = fminf(v0, __shfl_xor(v0, m, 64));
            v1 = fminf(v1, __shfl_xor(v1, m, 64));
            v2 = fminf(v2, __shfl_xor(v2, m, 64));
            v3 = fminf(v3, __shfl_xor(v3, m, 64));
        }
        if (seg == 0)
            contrib = fp[f0  ] * fmaxf(v0 + q0.w, 0.f)
                    + fp[f0+1] * fmaxf(v1 + q1.w, 0.f)
                    + fp[f0+2] * fmaxf(v2 + q2.w, 0.f)
                    + fp[f0+3] * fmaxf(v3 + q3.w, 0.f);
    }

    float tot = block_reduce_sum(contrib);
    if (tid == 0) atomicAdd(out, tot);
}

extern "C" void kernel_launch(void* const* d_in, const int* in_sizes, int n_in,
                              void* d_out, int out_size, void* d_ws, size_t ws_size,
                              hipStream_t stream) {
    const float* sv  = (const float*)d_in[0];   // (1,2048,3)
    const int*   sf  = (const int*)  d_in[1];   // (4096,3)
    const float* tv  = (const float*)d_in[2];   // (1,2048,3)
    const int*   tf  = (const int*)  d_in[3];   // (3,4096)
    const float* fp  = (const float*)d_in[4];   // (4096,)
    const float* r1u = (const float*)d_in[5];   // (4096,8)
    const float* r2u = (const float*)d_in[6];   // (4096,8)
    float* out = (float*)d_out;

    char* ws = (char*)d_ws;
    float4* sbc2 = (float4*)(ws);                 // 64 KB
    float4* tbc2 = (float4*)(ws + 65536);         // 64 KB
    float4* sbcr = (float4*)(ws + 131072);        // 64 KB

    k_prep<<<16,   256, 0, stream>>>(sv, sf, tv, tf, sbc2, tbc2, sbcr, out);
    k_main<<<1152, 256, 0, stream>>>(sv, sf, fp, r1u, r2u, sbc2, tbc2, sbcr, out);
}

// Round 13
// 120.215 us; speedup vs baseline: 1.0823x; 1.0823x over previous
//
#include <hip/hip_runtime.h>
#include <math.h>

#define FS 4096
#define FT 4096
#define TS 1024          // candidates per LDS tile (float4 -> 16 KB)
#define BIGF 3.0e38f
#define KEYINF 0xFFFFFFFFu

__device__ __forceinline__ unsigned umin32(unsigned a, unsigned b) { return a < b ? a : b; }
__device__ __forceinline__ unsigned umax32(unsigned a, unsigned b) { return a < b ? b : a; }

// v_med3_u32: median of 3 — one VOP3 instruction on gfx950
__device__ __forceinline__ unsigned med3u(unsigned a, unsigned b, unsigned c) {
    unsigned d;
    asm("v_med3_u32 %0, %1, %2, %3" : "=v"(d) : "v"(a), "v"(b), "v"(c));
    return d;
}

// ---------- block reduction helper (all threads must call) ----------
__device__ __forceinline__ float block_reduce_sum(float v) {
    __shared__ float s[8];
    for (int o = 32; o > 0; o >>= 1) v += __shfl_down(v, o, 64);
    int lane = threadIdx.x & 63, wid = threadIdx.x >> 6;
    if (lane == 0) s[wid] = v;
    __syncthreads();
    int nw = blockDim.x >> 6;
    v = (threadIdx.x < (unsigned)nw) ? s[threadIdx.x] : 0.f;
    if (wid == 0)
        for (int o = 4; o > 0; o >>= 1) v += __shfl_down(v, o, 64);
    return v;  // valid in thread 0
}

// compare-exchange on packed keys
#define CE(x, y) { unsigned _n = umin32(x, y); y = umax32(x, y); x = _n; }

// bitonic merge across 32-lane seg groups of sorted-6 lists (INF-pad to 8);
// all lanes end with the merged top-6.
__device__ __forceinline__ void merge32(unsigned s[6]) {
    #pragma unroll
    for (int m = 1; m <= 16; m <<= 1) {
        unsigned b0 = __shfl_xor(s[0], m, 64), b1 = __shfl_xor(s[1], m, 64);
        unsigned b2 = __shfl_xor(s[2], m, 64), b3 = __shfl_xor(s[3], m, 64);
        unsigned b4 = __shfl_xor(s[4], m, 64), b5 = __shfl_xor(s[5], m, 64);
        unsigned l0 = s[0], l1 = s[1];
        unsigned l2 = umin32(s[2], b5), l3 = umin32(s[3], b4);
        unsigned l4 = umin32(s[4], b3), l5 = umin32(s[5], b2);
        unsigned l6 = b1, l7 = b0;
        CE(l0, l4) CE(l1, l5) CE(l2, l6) CE(l3, l7)
        CE(l0, l2) CE(l1, l3) CE(l4, l6) CE(l5, l7)
        CE(l0, l1) CE(l2, l3) CE(l4, l5) CE(l6, l7)
        s[0] = l0; s[1] = l1; s[2] = l2; s[3] = l3; s[4] = l4; s[5] = l5;
    }
}

// ---------- precompute barycenters; zero the output accumulator ----------
// sbc2/tbc2: candidate form (-2x, -2y, -2z, |c|^2)  => dist = p2 + dot3(p, c.xyz) + c.w
// sbcr: raw source barycenter with .w = |bc|^2 (forward query points)
__global__ __launch_bounds__(256) void k_prep(
        const float* __restrict__ sv, const int* __restrict__ sf,
        const float* __restrict__ tv, const int* __restrict__ tf,
        float4* __restrict__ sbc2, float4* __restrict__ tbc2,
        float4* __restrict__ sbcr, float* __restrict__ out) {
    int i = blockIdx.x * blockDim.x + threadIdx.x;
    if (i == 0) out[0] = 0.f;
    if (i >= FS) return;
    const float third = 1.f / 3.f;
    int a = sf[3*i], b = sf[3*i+1], c = sf[3*i+2];
    float x = (sv[3*a  ] + sv[3*b  ] + sv[3*c  ]) * third;
    float y = (sv[3*a+1] + sv[3*b+1] + sv[3*c+1]) * third;
    float z = (sv[3*a+2] + sv[3*b+2] + sv[3*c+2]) * third;
    float n2 = x*x + y*y + z*z;
    sbc2[i] = make_float4(-2.f*x, -2.f*y, -2.f*z, n2);
    sbcr[i] = make_float4(x, y, z, n2);
    int ta = tf[i], tb = tf[FT + i], tc = tf[2*FT + i];
    float tx = (tv[3*ta  ] + tv[3*tb  ] + tv[3*tc  ]) * third;
    float ty = (tv[3*ta+1] + tv[3*tb+1] + tv[3*tc+1]) * third;
    float tz = (tv[3*ta+2] + tv[3*tb+2] + tv[3*tc+2]) * third;
    tbc2[i] = make_float4(-2.f*tx, -2.f*ty, -2.f*tz, tx*tx + ty*ty + tz*tz);
}

// ---------- fused main kernel: 1152 blocks x 256 threads, LDS-staged ----------
// 256 threads = 8 slots x 32 segments. Each slot owns 4 points (or 4 faces).
// Per tile-phase each segment scans TS/32 = 32 candidates from LDS.
// blocks [0,1024)    : reverse loss — 32 points/block
// blocks [1024,1152) : forward loss — 32 faces/block
__global__ __launch_bounds__(256, 4) void k_main(
        const float* __restrict__ sv, const int* __restrict__ sf,
        const float* __restrict__ fp,
        const float* __restrict__ r1u, const float* __restrict__ r2u,
        const float4* __restrict__ sbc2, const float4* __restrict__ tbc2,
        const float4* __restrict__ sbcr, float* __restrict__ out) {
    __shared__ float4 tile[TS];
    int tid  = threadIdx.x;
    int seg  = tid & 31;
    int slot = tid >> 5;
    float contrib = 0.f;

    if (blockIdx.x < 1024) {
        // ================= reverse =================
        int pt0  = blockIdx.x * 32 + slot * 4;   // this thread's 4 points
        int face = pt0 >> 3;                      // all 4 share one face

        int a = sf[3*face], b = sf[3*face+1], c = sf[3*face+2];
        float ax = sv[3*a], ay = sv[3*a+1], az = sv[3*a+2];
        float bx = sv[3*b], by = sv[3*b+1], bz = sv[3*b+2];
        float cx = sv[3*c], cy = sv[3*c+1], cz = sv[3*c+2];
        float4 r14 = ((const float4*)r1u)[pt0 >> 2];
        float4 r24 = ((const float4*)r2u)[pt0 >> 2];
        float px[4], py[4], pz[4], p2[4];
        {
            float r1a[4] = {r14.x, r14.y, r14.z, r14.w};
            float r2a[4] = {r24.x, r24.y, r24.z, r24.w};
            #pragma unroll
            for (int i = 0; i < 4; ++i) {
                float r1 = sqrtf(r1a[i]);
                float w1 = 1.f - r1, w2 = r1 * (1.f - r2a[i]), w3 = r1 * r2a[i];
                px[i] = w1*ax + w2*bx + w3*cx;
                py[i] = w1*ay + w2*by + w3*cy;
                pz[i] = w1*az + w2*bz + w3*cz;
                p2[i] = px[i]*px[i] + py[i]*py[i] + pz[i]*pz[i];
            }
        }

        // ---- src scan: per-lane top-3 per point (min + 2 med3 per eval) ----
        // Merged 32-lane result == exact top-6 unless one 128-candidate
        // segment holds >=4 of the global top-6 (validated exact since R7).
        unsigned s0[4], s1[4], s2[4];
        #pragma unroll
        for (int i = 0; i < 4; ++i) { s0[i]=KEYINF; s1[i]=KEYINF; s2[i]=KEYINF; }

        for (int t0 = 0; t0 < FS; t0 += TS) {
            #pragma unroll
            for (int j = 0; j < 4; ++j) tile[tid + j*256] = sbc2[t0 + tid + j*256];
            __syncthreads();
            unsigned jj = (unsigned)(t0 + seg);
            #pragma unroll 4
            for (int jp = 0; jp < TS/32; ++jp) {
                float4 c4 = tile[(jp << 5) + seg];
                #pragma unroll
                for (int i = 0; i < 4; ++i) {
                    // d = |p-c|^2 (unclamped; tiny-negative rounding sorts last)
                    float d = fmaf(px[i], c4.x, fmaf(py[i], c4.y,
                              fmaf(pz[i], c4.z, c4.w + p2[i])));
                    unsigned k = (__float_as_uint(d) & 0xFFFFF000u) | jj;
                    unsigned n0 = umin32(s0[i], k);
                    unsigned n1 = med3u(s0[i], s1[i], k);
                    unsigned n2 = med3u(s1[i], s2[i], k);
                    s0[i]=n0; s1[i]=n1; s2[i]=n2;
                }
                jj += 32;
            }
            __syncthreads();
        }

        // ---- tgt scan: 4 mins (v-space, +p2 at the end) ----
        float vm[4] = {BIGF, BIGF, BIGF, BIGF};
        for (int t0 = 0; t0 < FT; t0 += TS) {
            #pragma unroll
            for (int j = 0; j < 4; ++j) tile[tid + j*256] = tbc2[t0 + tid + j*256];
            __syncthreads();
            #pragma unroll 4
            for (int jp = 0; jp < TS/32; ++jp) {
                float4 c4 = tile[(jp << 5) + seg];
                #pragma unroll
                for (int i = 0; i < 4; ++i) {
                    float v = fmaf(px[i], c4.x, fmaf(py[i], c4.y, fmaf(pz[i], c4.z, c4.w)));
                    vm[i] = fminf(vm[i], v);
                }
            }
            __syncthreads();
        }

        // ---- merges across the 32-lane seg group ----
        #pragma unroll
        for (int i = 0; i < 4; ++i) {
            float v = vm[i];
            v = fminf(v, __shfl_xor(v, 1, 64));
            v = fminf(v, __shfl_xor(v, 2, 64));
            v = fminf(v, __shfl_xor(v, 4, 64));
            v = fminf(v, __shfl_xor(v, 8, 64));
            v = fminf(v, __shfl_xor(v, 16, 64));
            vm[i] = v;
        }

        float pf = fp[face];
        float csum = 0.f;
        #pragma unroll
        for (int i = 0; i < 4; ++i) {
            unsigned srt[6] = {s0[i], s1[i], s2[i], KEYINF, KEYINF, KEYINF};
            merge32(srt);
            if (seg == 0) {
                int   q0 = srt[0] & 0xFFF, q1 = srt[1] & 0xFFF, q2 = srt[2] & 0xFFF;
                int   q3 = srt[3] & 0xFFF, q4 = srt[4] & 0xFFF, q5 = srt[5] & 0xFFF;
                float d0 = __uint_as_float(srt[0] & 0xFFFFF000u);
                float d1 = __uint_as_float(srt[1] & 0xFFFFF000u);
                float d2 = __uint_as_float(srt[2] & 0xFFFFF000u);
                float d3 = __uint_as_float(srt[3] & 0xFFFFF000u);
                float d4 = __uint_as_float(srt[4] & 0xFFFFF000u);
                float d5 = __uint_as_float(srt[5] & 0xFFFFF000u);

                int skip = 5;
                if      (q0 == face) skip = 0;
                else if (q1 == face) skip = 1;
                else if (q2 == face) skip = 2;
                else if (q3 == face) skip = 3;
                else if (q4 == face) skip = 4;

                float s = 0.f;
                if (skip != 0) s += fp[q0] * d0;
                if (skip != 1) s += fp[q1] * d1;
                if (skip != 2) s += fp[q2] * d2;
                if (skip != 3) s += fp[q3] * d3;
                if (skip != 4) s += fp[q4] * d4;
                if (skip != 5) s += fp[q5] * d5;

                float mtd = fmaxf(vm[i] + p2[i], 0.f);
                csum += pf * mtd + (1.f - pf) * (s * 0.2f);
            }
        }
        if (seg == 0) contrib = csum;
    } else {
        // ================= forward =================
        int f0 = (blockIdx.x - 1024) * 32 + slot * 4;   // this thread's 4 faces
        float4 q0 = sbcr[f0], q1 = sbcr[f0+1], q2 = sbcr[f0+2], q3 = sbcr[f0+3];
        float v0 = BIGF, v1 = BIGF, v2 = BIGF, v3 = BIGF;
        for (int t0 = 0; t0 < FT; t0 += TS) {
            #pragma unroll
            for (int j = 0; j < 4; ++j) tile[tid + j*256] = tbc2[t0 + tid + j*256];
            __syncthreads();
            #pragma unroll 4
            for (int jp = 0; jp < TS/32; ++jp) {
                float4 c4 = tile[(jp << 5) + seg];
                v0 = fminf(v0, fmaf(q0.x, c4.x, fmaf(q0.y, c4.y, fmaf(q0.z, c4.z, c4.w))));
                v1 = fminf(v1, fmaf(q1.x, c4.x, fmaf(q1.y, c4.y, fmaf(q1.z, c4.z, c4.w))));
                v2 = fminf(v2, fmaf(q2.x, c4.x, fmaf(q2.y, c4.y, fmaf(q2.z, c4.z, c4.w))));
                v3 = fminf(v3, fmaf(q3.x, c4.x, fmaf(q3.y, c4.y, fmaf(q3.z, c4.z, c4.w))));
            }
            __syncthreads();
        }
        #pragma unroll
        for (int m = 1; m <= 16; m <<= 1) {
            v0 = fminf(v0, __shfl_xor(v0, m, 64));
            v1 = fminf(v1, __shfl_xor(v1, m, 64));
            v2 = fminf(v2, __shfl_xor(v2, m, 64));
            v3 = fminf(v3, __shfl_xor(v3, m, 64));
        }
        if (seg == 0)
            contrib = fp[f0  ] * fmaxf(v0 + q0.w, 0.f)
                    + fp[f0+1] * fmaxf(v1 + q1.w, 0.f)
                    + fp[f0+2] * fmaxf(v2 + q2.w, 0.f)
                    + fp[f0+3] * fmaxf(v3 + q3.w, 0.f);
    }

    float tot = block_reduce_sum(contrib);
    if (tid == 0) atomicAdd(out, tot);
}

extern "C" void kernel_launch(void* const* d_in, const int* in_sizes, int n_in,
                              void* d_out, int out_size, void* d_ws, size_t ws_size,
                              hipStream_t stream) {
    const float* sv  = (const float*)d_in[0];   // (1,2048,3)
    const int*   sf  = (const int*)  d_in[1];   // (4096,3)
    const float* tv  = (const float*)d_in[2];   // (1,2048,3)
    const int*   tf  = (const int*)  d_in[3];   // (3,4096)
    const float* fp  = (const float*)d_in[4];   // (4096,)
    const float* r1u = (const float*)d_in[5];   // (4096,8)
    const float* r2u = (const float*)d_in[6];   // (4096,8)
    float* out = (float*)d_out;

    char* ws = (char*)d_ws;
    float4* sbc2 = (float4*)(ws);                 // 64 KB
    float4* tbc2 = (float4*)(ws + 65536);         // 64 KB
    float4* sbcr = (float4*)(ws + 131072);        // 64 KB

    k_prep<<<16,   256, 0, stream>>>(sv, sf, tv, tf, sbc2, tbc2, sbcr, out);
    k_main<<<1152, 256, 0, stream>>>(sv, sf, fp, r1u, r2u, sbc2, tbc2, sbcr, out);
}

// Round 14
// 119.039 us; speedup vs baseline: 1.0930x; 1.0099x over previous
//
#include <hip/hip_runtime.h>
#include <math.h>

#define FS 4096
#define FT 4096
#define TS 1024          // candidates per LDS tile (float4 -> 16 KB each, x2 tiles)
#define BIGF 3.0e38f
#define KEYINF 0xFFFFFFFFu

__device__ __forceinline__ unsigned umin32(unsigned a, unsigned b) { return a < b ? a : b; }
__device__ __forceinline__ unsigned umax32(unsigned a, unsigned b) { return a < b ? b : a; }

// v_med3_u32: median of 3 — one VOP3 instruction on gfx950
__device__ __forceinline__ unsigned med3u(unsigned a, unsigned b, unsigned c) {
    unsigned d;
    asm("v_med3_u32 %0, %1, %2, %3" : "=v"(d) : "v"(a), "v"(b), "v"(c));
    return d;
}

// ---------- block reduction helper (all threads must call) ----------
__device__ __forceinline__ float block_reduce_sum(float v) {
    __shared__ float s[8];
    for (int o = 32; o > 0; o >>= 1) v += __shfl_down(v, o, 64);
    int lane = threadIdx.x & 63, wid = threadIdx.x >> 6;
    if (lane == 0) s[wid] = v;
    __syncthreads();
    int nw = blockDim.x >> 6;
    v = (threadIdx.x < (unsigned)nw) ? s[threadIdx.x] : 0.f;
    if (wid == 0)
        for (int o = 4; o > 0; o >>= 1) v += __shfl_down(v, o, 64);
    return v;  // valid in thread 0
}

// compare-exchange on packed keys
#define CE(x, y) { unsigned _n = umin32(x, y); y = umax32(x, y); x = _n; }

// bitonic merge across 32-lane seg groups of sorted-6 lists (INF-pad to 8);
// all lanes end with the merged top-6.
__device__ __forceinline__ void merge32(unsigned s[6]) {
    #pragma unroll
    for (int m = 1; m <= 16; m <<= 1) {
        unsigned b0 = __shfl_xor(s[0], m, 64), b1 = __shfl_xor(s[1], m, 64);
        unsigned b2 = __shfl_xor(s[2], m, 64), b3 = __shfl_xor(s[3], m, 64);
        unsigned b4 = __shfl_xor(s[4], m, 64), b5 = __shfl_xor(s[5], m, 64);
        unsigned l0 = s[0], l1 = s[1];
        unsigned l2 = umin32(s[2], b5), l3 = umin32(s[3], b4);
        unsigned l4 = umin32(s[4], b3), l5 = umin32(s[5], b2);
        unsigned l6 = b1, l7 = b0;
        CE(l0, l4) CE(l1, l5) CE(l2, l6) CE(l3, l7)
        CE(l0, l2) CE(l1, l3) CE(l4, l6) CE(l5, l7)
        CE(l0, l1) CE(l2, l3) CE(l4, l5) CE(l6, l7)
        s[0] = l0; s[1] = l1; s[2] = l2; s[3] = l3; s[4] = l4; s[5] = l5;
    }
}

// ---------- precompute barycenters; zero the output accumulator ----------
// sbc2/tbc2: candidate form (-2x, -2y, -2z, |c|^2)  => dist = p2 + dot3(p, c.xyz) + c.w
// sbcr: raw source barycenter with .w = |bc|^2 (forward query points)
__global__ __launch_bounds__(256) void k_prep(
        const float* __restrict__ sv, const int* __restrict__ sf,
        const float* __restrict__ tv, const int* __restrict__ tf,
        float4* __restrict__ sbc2, float4* __restrict__ tbc2,
        float4* __restrict__ sbcr, float* __restrict__ out) {
    int i = blockIdx.x * blockDim.x + threadIdx.x;
    if (i == 0) out[0] = 0.f;
    if (i >= FS) return;
    const float third = 1.f / 3.f;
    int a = sf[3*i], b = sf[3*i+1], c = sf[3*i+2];
    float x = (sv[3*a  ] + sv[3*b  ] + sv[3*c  ]) * third;
    float y = (sv[3*a+1] + sv[3*b+1] + sv[3*c+1]) * third;
    float z = (sv[3*a+2] + sv[3*b+2] + sv[3*c+2]) * third;
    float n2 = x*x + y*y + z*z;
    sbc2[i] = make_float4(-2.f*x, -2.f*y, -2.f*z, n2);
    sbcr[i] = make_float4(x, y, z, n2);
    int ta = tf[i], tb = tf[FT + i], tc = tf[2*FT + i];
    float tx = (tv[3*ta  ] + tv[3*tb  ] + tv[3*tc  ]) * third;
    float ty = (tv[3*ta+1] + tv[3*tb+1] + tv[3*tc+1]) * third;
    float tz = (tv[3*ta+2] + tv[3*tb+2] + tv[3*tc+2]) * third;
    tbc2[i] = make_float4(-2.f*tx, -2.f*ty, -2.f*tz, tx*tx + ty*ty + tz*tz);
}

// ---------- fused main kernel: 1152 blocks x 256 threads, dual-tile staged ----------
// Per phase p (4 total) stage BOTH src-tile-p and tgt-tile-p (32 KB), one
// barrier pair, then run sort-scan (src) + min-scan (tgt) back to back:
// halves barrier events vs single-tile staging, doubles compute per span.
// 256 threads = 8 slots x 32 segments. Each slot owns 4 points (or 4 faces).
// blocks [0,1024)    : reverse loss — 32 points/block
// blocks [1024,1152) : forward loss — 32 faces/block
__global__ __launch_bounds__(256, 4) void k_main(
        const float* __restrict__ sv, const int* __restrict__ sf,
        const float* __restrict__ fp,
        const float* __restrict__ r1u, const float* __restrict__ r2u,
        const float4* __restrict__ sbc2, const float4* __restrict__ tbc2,
        const float4* __restrict__ sbcr, float* __restrict__ out) {
    __shared__ float4 tileS[TS];
    __shared__ float4 tileT[TS];
    int tid  = threadIdx.x;
    int seg  = tid & 31;
    int slot = tid >> 5;
    float contrib = 0.f;

    if (blockIdx.x < 1024) {
        // ================= reverse =================
        int pt0  = blockIdx.x * 32 + slot * 4;   // this thread's 4 points
        int face = pt0 >> 3;                      // all 4 share one face

        int a = sf[3*face], b = sf[3*face+1], c = sf[3*face+2];
        float ax = sv[3*a], ay = sv[3*a+1], az = sv[3*a+2];
        float bx = sv[3*b], by = sv[3*b+1], bz = sv[3*b+2];
        float cx = sv[3*c], cy = sv[3*c+1], cz = sv[3*c+2];
        float4 r14 = ((const float4*)r1u)[pt0 >> 2];
        float4 r24 = ((const float4*)r2u)[pt0 >> 2];
        float px[4], py[4], pz[4], p2[4];
        {
            float r1a[4] = {r14.x, r14.y, r14.z, r14.w};
            float r2a[4] = {r24.x, r24.y, r24.z, r24.w};
            #pragma unroll
            for (int i = 0; i < 4; ++i) {
                float r1 = sqrtf(r1a[i]);
                float w1 = 1.f - r1, w2 = r1 * (1.f - r2a[i]), w3 = r1 * r2a[i];
                px[i] = w1*ax + w2*bx + w3*cx;
                py[i] = w1*ay + w2*by + w3*cy;
                pz[i] = w1*az + w2*bz + w3*cz;
                p2[i] = px[i]*px[i] + py[i]*py[i] + pz[i]*pz[i];
            }
        }

        // per-lane top-3 per point (min + 2 med3 per eval); exact merged top-6
        unsigned s0[4], s1[4], s2[4];
        #pragma unroll
        for (int i = 0; i < 4; ++i) { s0[i]=KEYINF; s1[i]=KEYINF; s2[i]=KEYINF; }
        float vm[4] = {BIGF, BIGF, BIGF, BIGF};

        for (int p = 0; p < 4; ++p) {
            int t0 = p * TS;
            #pragma unroll
            for (int j = 0; j < 4; ++j) {
                tileS[tid + j*256] = sbc2[t0 + tid + j*256];
                tileT[tid + j*256] = tbc2[t0 + tid + j*256];
            }
            __syncthreads();
            // ---- src sort-scan ----
            unsigned jj = (unsigned)(t0 + seg);
            #pragma unroll 4
            for (int jp = 0; jp < TS/32; ++jp) {
                float4 c4 = tileS[(jp << 5) + seg];
                #pragma unroll
                for (int i = 0; i < 4; ++i) {
                    // d = |p-c|^2 (unclamped; tiny-negative rounding sorts last)
                    float d = fmaf(px[i], c4.x, fmaf(py[i], c4.y,
                              fmaf(pz[i], c4.z, c4.w + p2[i])));
                    unsigned k = (__float_as_uint(d) & 0xFFFFF000u) | jj;
                    unsigned n0 = umin32(s0[i], k);
                    unsigned n1 = med3u(s0[i], s1[i], k);
                    unsigned n2 = med3u(s1[i], s2[i], k);
                    s0[i]=n0; s1[i]=n1; s2[i]=n2;
                }
                jj += 32;
            }
            // ---- tgt min-scan ----
            #pragma unroll 4
            for (int jp = 0; jp < TS/32; ++jp) {
                float4 c4 = tileT[(jp << 5) + seg];
                #pragma unroll
                for (int i = 0; i < 4; ++i) {
                    float v = fmaf(px[i], c4.x, fmaf(py[i], c4.y, fmaf(pz[i], c4.z, c4.w)));
                    vm[i] = fminf(vm[i], v);
                }
            }
            __syncthreads();
        }

        // ---- merges across the 32-lane seg group ----
        #pragma unroll
        for (int i = 0; i < 4; ++i) {
            float v = vm[i];
            v = fminf(v, __shfl_xor(v, 1, 64));
            v = fminf(v, __shfl_xor(v, 2, 64));
            v = fminf(v, __shfl_xor(v, 4, 64));
            v = fminf(v, __shfl_xor(v, 8, 64));
            v = fminf(v, __shfl_xor(v, 16, 64));
            vm[i] = v;
        }

        float pf = fp[face];
        float csum = 0.f;
        #pragma unroll
        for (int i = 0; i < 4; ++i) {
            unsigned srt[6] = {s0[i], s1[i], s2[i], KEYINF, KEYINF, KEYINF};
            merge32(srt);
            if (seg == 0) {
                int   q0 = srt[0] & 0xFFF, q1 = srt[1] & 0xFFF, q2 = srt[2] & 0xFFF;
                int   q3 = srt[3] & 0xFFF, q4 = srt[4] & 0xFFF, q5 = srt[5] & 0xFFF;
                float d0 = __uint_as_float(srt[0] & 0xFFFFF000u);
                float d1 = __uint_as_float(srt[1] & 0xFFFFF000u);
                float d2 = __uint_as_float(srt[2] & 0xFFFFF000u);
                float d3 = __uint_as_float(srt[3] & 0xFFFFF000u);
                float d4 = __uint_as_float(srt[4] & 0xFFFFF000u);
                float d5 = __uint_as_float(srt[5] & 0xFFFFF000u);

                int skip = 5;
                if      (q0 == face) skip = 0;
                else if (q1 == face) skip = 1;
                else if (q2 == face) skip = 2;
                else if (q3 == face) skip = 3;
                else if (q4 == face) skip = 4;

                float s = 0.f;
                if (skip != 0) s += fp[q0] * d0;
                if (skip != 1) s += fp[q1] * d1;
                if (skip != 2) s += fp[q2] * d2;
                if (skip != 3) s += fp[q3] * d3;
                if (skip != 4) s += fp[q4] * d4;
                if (skip != 5) s += fp[q5] * d5;

                float mtd = fmaxf(vm[i] + p2[i], 0.f);
                csum += pf * mtd + (1.f - pf) * (s * 0.2f);
            }
        }
        if (seg == 0) contrib = csum;
    } else {
        // ================= forward =================
        int f0 = (blockIdx.x - 1024) * 32 + slot * 4;   // this thread's 4 faces
        float4 q0 = sbcr[f0], q1 = sbcr[f0+1], q2 = sbcr[f0+2], q3 = sbcr[f0+3];
        float v0 = BIGF, v1 = BIGF, v2 = BIGF, v3 = BIGF;
        for (int p = 0; p < 4; ++p) {
            int t0 = p * TS;
            #pragma unroll
            for (int j = 0; j < 4; ++j) tileT[tid + j*256] = tbc2[t0 + tid + j*256];
            __syncthreads();
            #pragma unroll 4
            for (int jp = 0; jp < TS/32; ++jp) {
                float4 c4 = tileT[(jp << 5) + seg];
                v0 = fminf(v0, fmaf(q0.x, c4.x, fmaf(q0.y, c4.y, fmaf(q0.z, c4.z, c4.w))));
                v1 = fminf(v1, fmaf(q1.x, c4.x, fmaf(q1.y, c4.y, fmaf(q1.z, c4.z, c4.w))));
                v2 = fminf(v2, fmaf(q2.x, c4.x, fmaf(q2.y, c4.y, fmaf(q2.z, c4.z, c4.w))));
                v3 = fminf(v3, fmaf(q3.x, c4.x, fmaf(q3.y, c4.y, fmaf(q3.z, c4.z, c4.w))));
            }
            __syncthreads();
        }
        #pragma unroll
        for (int m = 1; m <= 16; m <<= 1) {
            v0 = fminf(v0, __shfl_xor(v0, m, 64));
            v1 = fminf(v1, __shfl_xor(v1, m, 64));
            v2 = fminf(v2, __shfl_xor(v2, m, 64));
            v3 = fminf(v3, __shfl_xor(v3, m, 64));
        }
        if (seg == 0)
            contrib = fp[f0  ] * fmaxf(v0 + q0.w, 0.f)
                    + fp[f0+1] * fmaxf(v1 + q1.w, 0.f)
                    + fp[f0+2] * fmaxf(v2 + q2.w, 0.f)
                    + fp[f0+3] * fmaxf(v3 + q3.w, 0.f);
    }

    float tot = block_reduce_sum(contrib);
    if (tid == 0) atomicAdd(out, tot);
}

extern "C" void kernel_launch(void* const* d_in, const int* in_sizes, int n_in,
                              void* d_out, int out_size, void* d_ws, size_t ws_size,
                              hipStream_t stream) {
    const float* sv  = (const float*)d_in[0];   // (1,2048,3)
    const int*   sf  = (const int*)  d_in[1];   // (4096,3)
    const float* tv  = (const float*)d_in[2];   // (1,2048,3)
    const int*   tf  = (const int*)  d_in[3];   // (3,4096)
    const float* fp  = (const float*)d_in[4];   // (4096,)
    const float* r1u = (const float*)d_in[5];   // (4096,8)
    const float* r2u = (const float*)d_in[6];   // (4096,8)
    float* out = (float*)d_out;

    char* ws = (char*)d_ws;
    float4* sbc2 = (float4*)(ws);                 // 64 KB
    float4* tbc2 = (float4*)(ws + 65536);         // 64 KB
    float4* sbcr = (float4*)(ws + 131072);        // 64 KB

    k_prep<<<16,   256, 0, stream>>>(sv, sf, tv, tf, sbc2, tbc2, sbcr, out);
    k_main<<<1152, 256, 0, stream>>>(sv, sf, fp, r1u, r2u, sbc2, tbc2, sbcr, out);
}